// Round 7
// baseline (312.782 us; speedup 1.0000x reference)
//
#include <hip/hip_runtime.h>
#include <stdint.h>

// Tree-LSTM scan: B=256, L=128, STATE=128, INIT=256, Z=5*128=640. fp32 I/O.
// Pipeline:
//  (0) whx_w fp32->bf16 into d_ws (full 640x256).
//  (1) zx_gemm: Zx[t*256+b][640] = W_x @ embed[ids[b,t]][0:128] + bias, fp32,
//      full-GPU MFMA GEMM with fused gather+bias, swapped operands (A=W,B=X)
//      -> per-lane float4 NONTEMPORAL stores (R4 evidence: nt saves ~6us).
//  (2) scan: 32 blocks x 512 threads, 8 batch rows/block, mirrored MFMA
//      B-cols, W_h register-resident, h LDS XOR-swizzled, raw v_exp_f32
//      gates. NEW (R7): the per-step barrier is a RAW s_barrier preceded by
//      lgkmcnt(0) ONLY -- __syncthreads()'s implicit vmcnt(0) was draining
//      the Zx/right_c prefetch (60% HBM-served, ~900cy) on the critical
//      path of EVERY step. With the raw barrier the prefetch stays in
//      flight across the barrier; the compiler's register-dep vmcnt wait
//      at next step's acc-init is the consumption point (T4/m139 pattern).

constexpr int kL      = 128;
constexpr int kState  = 128;
constexpr int kInit   = 256;
constexpr int kRows   = 8;                      // batch rows per scan block
constexpr int kBlocks = 32;
constexpr int kThreads= 512;
constexpr int kWElems = 5 * kState * kInit;     // 163840 (320 KiB bf16)
constexpr int kNTot   = 256 * kL;               // 32768 (t,b) rows
constexpr int kZxCols = 5 * kState;             // 640

typedef __attribute__((ext_vector_type(8))) short short8;    // MFMA A/B frag
typedef __attribute__((ext_vector_type(4))) short short4v;
typedef __attribute__((ext_vector_type(4))) float floatx4;   // MFMA C/D frag

__device__ __forceinline__ uint16_t f2bf(float f) {
    union { float f; uint32_t i; } v; v.f = f;
    return (uint16_t)((v.i + 0x7FFFu + ((v.i >> 16) & 1u)) >> 16);  // RNE
}
__device__ __forceinline__ float bf2f(uint16_t u) {
    union { uint32_t i; float f; } v; v.i = ((uint32_t)u) << 16; return v.f;
}
__device__ __forceinline__ float fexp2(float x) {
    return __builtin_amdgcn_exp2f(x);           // raw v_exp_f32
}
// Raw barrier: order LDS (h publish) but let VMEM prefetch stay in flight.
__device__ __forceinline__ void bar_lds_only() {
    asm volatile("s_waitcnt lgkmcnt(0)" ::: "memory");
    __builtin_amdgcn_sched_barrier(0);
    __builtin_amdgcn_s_barrier();
    __builtin_amdgcn_sched_barrier(0);
}

// ---- kernel 0: whx_w fp32 -> bf16 (row-major 640x256) ----
__global__ __launch_bounds__(256)
void convert_weights_kernel(const float* __restrict__ wsrc,
                            uint16_t* __restrict__ wdst) {
    int i = blockIdx.x * 256 + threadIdx.x;          // float4 index
    float4 v = ((const float4*)wsrc)[i];
    uint16_t q[4] = { f2bf(v.x), f2bf(v.y), f2bf(v.z), f2bf(v.w) };
    ((short4v*)wdst)[i] = *(short4v*)q;
}

// ---- kernel 1: Zx[n][j] = sum_k W[j][128+k]*embed[id(n)][k] + bias[j] ----
// Swapped operands: A = W_x rows (lane l15 = j mod 16), B = X (lane l15 = n
// mod 16, k = quad*8+e). D: row = quad*4+r = j-local (consecutive!), col =
// l15 = n -> per-lane float4 nt store zx[n0+l15][jf*16+quad*4 .. +3].
__global__ __launch_bounds__(256)
void zx_gemm_kernel(const uint16_t* __restrict__ wbf,
                    const float* __restrict__ embed,
                    const int* __restrict__ ids,
                    const float* __restrict__ whx_b,
                    float* __restrict__ zx)
{
    const int wv   = threadIdx.x >> 6;
    const int lane = threadIdx.x & 63;
    const int l15  = lane & 15;
    const int quad = lane >> 4;
    const int n0   = (blockIdx.x * 4 + wv) * 16;
    const int T    = n0 >> 8;                  // timestep
    const int B    = (n0 & 255) + l15;         // batch row (n col) for lane
    const int id   = ids[B * kL + T];

    // B-frag: X[k, n] -- lane's own embed row, bf16-converted
    short8 xf[4];
    const float* xr = embed + (size_t)id * kInit;   // right_h = cols 0..127
#pragma unroll
    for (int kk = 0; kk < 4; ++kk) {
        float4 v0 = *(const float4*)(xr + kk * 32 + quad * 8);
        float4 v1 = *(const float4*)(xr + kk * 32 + quad * 8 + 4);
        uint16_t q[8] = { f2bf(v0.x), f2bf(v0.y), f2bf(v0.z), f2bf(v0.w),
                          f2bf(v1.x), f2bf(v1.y), f2bf(v1.z), f2bf(v1.w) };
        xf[kk] = *(short8*)q;
    }

    float* zrow = zx + (size_t)(n0 + l15) * kZxCols;
#pragma unroll 4
    for (int jf = 0; jf < 40; ++jf) {
        // A-frag: W rows j = jf*16 + l15, x-part cols
        const uint16_t* wr = wbf + (size_t)(jf * 16 + l15) * kInit + kState;
        // bias for the 4 owned j rows (quad*4 .. +3), same for all l15
        floatx4 acc = *(const floatx4*)(whx_b + jf * 16 + quad * 4);
#pragma unroll
        for (int kk = 0; kk < 4; ++kk) {
            short8 wa = *(const short8*)(wr + kk * 32 + quad * 8);
            acc = __builtin_amdgcn_mfma_f32_16x16x32_bf16(wa, xf[kk], acc, 0, 0, 0);
        }
        __builtin_nontemporal_store(acc, (floatx4*)(zrow + jf * 16 + quad * 4));
    }
}

// ---- kernel 2: the scan (h-recurrence only, K=128) ----
__global__ __launch_bounds__(kThreads)
__attribute__((amdgpu_waves_per_eu(1, 2)))
void tree_lstm_kernel(const uint16_t* __restrict__ wbf,
                      const float* __restrict__ zx,
                      const float* __restrict__ embed,
                      const int* __restrict__ ids,
                      const float* __restrict__ init_state,
                      const float* __restrict__ final_w,
                      const float* __restrict__ final_b,
                      float* __restrict__ out)
{
    // swizzled: element (row, col) lives at [row][ ((col>>3)^row)*8 + (col&7) ]
    // rows 8..15 mirror rows 0..7 (dual-write) -> MFMA D cols 8..15 mirror.
    __shared__ alignas(16) uint16_t hb[2][16][kState];      // 8 KB  (h)
    __shared__ int ids_l[kL][kRows];                        // 4 KB, [t][b]
    __shared__ float partial[kRows][3][4];
    // >80 KiB total => exactly 1 workgroup/CU.
    __shared__ float lds_force_pad[18432];                  // 72 KiB

    const int tid  = threadIdx.x;
    const int w    = tid >> 6;        // wave 0..7 -> j-slice [16w,16w+16)
    const int lane = tid & 63;
    const int l15  = lane & 15;       // MFMA D col (batch, mirrored over 8)
    const int quad = lane >> 4;       // 0..3
    const int b0   = blockIdx.x * kRows;
    const int j0   = w * 16 + quad * 4;   // 4 consecutive j (MFMA D rows)
    const int bl   = l15 & 7;             // owned batch row
    const bool hig = l15 >= 8;            // owns r-slots {2,3}
    const int jp   = j0 + (hig ? 2 : 0);  // first owned j

    if (__builtin_expect(ids[0] < 0, 0)) {      // never true; keeps pad alive
        volatile float* vp = lds_force_pad;
        vp[tid] = (float)tid;
        float v = vp[(tid * 7) & 16383];
        if (v < -1.0e30f) out[0] = v;
    }

    // stage ids transposed [t][b]
    for (int i = tid; i < kL * kRows; i += kThreads)
        ids_l[i >> 3][i & 7] = ids[(b0 + (i & 7)) * kL + (i >> 3)];

    // register-resident A-frags, h-part only (cols 0..127): 40 VGPRs
    short8 wf[5][4];
#pragma unroll
    for (int g = 0; g < 5; ++g) {
        const uint16_t* wrow = wbf + (size_t)(g * 128 + w * 16 + l15) * kInit;
#pragma unroll
        for (int kk = 0; kk < 4; ++kk)
            wf[g][kk] = *(const short8*)(wrow + kk * 32 + quad * 8);
    }

    // h0 (bf16, swizzled into hb[0]; all 16 rows incl. mirrors get identical
    // broadcast values) and c0 (fp32 regs for the 2 owned slots)
    const int g8   = 2 * w + (quad >> 1);                // col group of j0/jp
    const int hoff = (g8 ^ l15) * 8 + (quad & 1) * 4;    // h0 write offset
    float c_reg[2];
    {
        uint16_t h0[4];
#pragma unroll
        for (int r = 0; r < 4; ++r)
            h0[r] = f2bf(init_state[j0 + r]);
        c_reg[0] = init_state[128 + jp];
        c_reg[1] = init_state[128 + jp + 1];
        *(short4v*)&hb[0][l15][hoff] = *(short4v*)h0;
    }
    __syncthreads();   // prologue barrier: ids_l + h0 visible (full drain ok)

    // per-step h write: 2 bf16 (4 B) to row bl AND mirror row bl+8
    const int eoff  = (quad & 1) * 4 + (hig ? 2 : 0);    // jp & 7
    const int wlo   = (g8 ^ bl) * 8 + eoff;
    const int whi   = ((g8 ^ bl) ^ 8) * 8 + eoff;

    // register double-buffer for Zx (acc init; row clamped to bl so mirror
    // cols get duplicates) and right_c (2 owned values); literal-indexed
    floatx4 zbuf[2][5];
    float2  rbuf[2];
    {
        const float* zr = zx + ((size_t)b0 + bl) * kZxCols + j0;   // t=0
#pragma unroll
        for (int g = 0; g < 5; ++g)
            zbuf[0][g] = *(const floatx4*)(zr + g * 128);
        int id0 = ids_l[0][bl];
        rbuf[0] = *(const float2*)(embed + (size_t)id0 * kInit + kState + jp);
    }

    const float K1 = 1.442695041f;   // log2(e)
    const float K2 = 2.885390082f;   // 2*log2(e)

    // One gate cell. RL = literal r (0/1); select mirrors via cndmask.
    // fminf-only clamps: unclamped directions are safe (Inf -> rcp -> 0;
    // v_exp_f32 handles +-Inf inputs with the correct limits).
#define GATE_CELL(RL, RCV, HVOUT)                                              \
    {                                                                          \
        float ga = hig ? acc[0][RL + 2] : acc[0][RL];                          \
        float gi = hig ? acc[1][RL + 2] : acc[1][RL];                          \
        float g1 = hig ? acc[2][RL + 2] : acc[2][RL];                          \
        float g2 = hig ? acc[3][RL + 2] : acc[3][RL];                          \
        float go = hig ? acc[4][RL + 2] : acc[4][RL];                          \
        float a  = fminf(ga, 15.f);                                            \
        float f1 = fminf(g1, 30.f);                                            \
        float f2 = fminf(g2, 30.f);                                            \
        float Ea = fexp2(a * K2);                 /* e^{2a} */                 \
        float Ei = fexp2(-gi * K1);               /* e^{-i} */                 \
        float P  = (Ea - 1.0f) *                                               \
            __builtin_amdgcn_rcpf((Ea + 1.0f) * (1.0f + Ei));                  \
        float E1 = fexp2(f1 * K1), E2 = fexp2(f2 * K1);                        \
        float lc = c_reg[RL], rc = (RCV);                                      \
        float num = E1 * (1.0f + E2) * lc + E2 * (1.0f + E1) * rc;             \
        float Q  = num * __builtin_amdgcn_rcpf((1.0f + E1) * (1.0f + E2));     \
        float c  = P + Q;                                                      \
        c_reg[RL] = c;                                                         \
        float Eo = fexp2(-go * K1);                                            \
        float cc = fminf(c, 15.f);                                             \
        float Ec = fexp2(cc * K2);                                             \
        float h  = (Ec - 1.0f) *                                               \
            __builtin_amdgcn_rcpf((1.0f + Eo) * (Ec + 1.0f));                  \
        HVOUT = f2bf(h);                                                       \
    }

#define LSTM_STEP(T, CUR, NXT)                                                 \
    {                                                                          \
        /* prefetch t+1; stays IN FLIGHT across the raw barrier below */       \
        int tn = (T) + 1; if (tn >= kL) tn = kL - 1;                           \
        const float* zr = zx + ((size_t)tn * 256 + b0 + bl) * kZxCols + j0;    \
        _Pragma("unroll")                                                      \
        for (int g = 0; g < 5; ++g)                                            \
            zbuf[NXT][g] = *(const floatx4*)(zr + g * 128);                    \
        int idn = ids_l[tn][bl];                                               \
        rbuf[NXT] = *(const float2*)(embed + (size_t)idn * kInit + kState + jp); \
        /* acc init = Zx (x-part + bias), then h-part MFMAs */                 \
        floatx4 acc[5];                                                        \
        _Pragma("unroll")                                                      \
        for (int g = 0; g < 5; ++g) acc[g] = zbuf[CUR][g];                     \
        const uint16_t* hrow = &hb[CUR][l15][0];                               \
        _Pragma("unroll")                                                      \
        for (int kk = 0; kk < 4; ++kk) {                                       \
            short8 xf = *(const short8*)(hrow + ((kk * 4 + quad) ^ l15) * 8);  \
            _Pragma("unroll")                                                  \
            for (int g = 0; g < 5; ++g)                                        \
                acc[g] = __builtin_amdgcn_mfma_f32_16x16x32_bf16(              \
                    wf[g][kk], xf, acc[g], 0, 0, 0);                           \
        }                                                                      \
        uint16_t hv0, hv1;                                                     \
        GATE_CELL(0, rbuf[CUR].x, hv0)                                         \
        GATE_CELL(1, rbuf[CUR].y, hv1)                                         \
        uint32_t hp = (uint32_t)hv0 | ((uint32_t)hv1 << 16);                   \
        *(uint32_t*)&hb[NXT][bl][wlo]     = hp;                                \
        *(uint32_t*)&hb[NXT][bl + 8][whi] = hp;                                \
        bar_lds_only();   /* lgkmcnt(0)+s_barrier: h published, VMEM flows */  \
    }

#pragma unroll 1
    for (int t2 = 0; t2 < kL; t2 += 2) {
        LSTM_STEP(t2, 0, 1)
        LSTM_STEP(t2 + 1, 1, 0)
    }
#undef LSTM_STEP
#undef GATE_CELL

    // final: out[b][o] = sum_j h[b][j]*final_w[o][j] + final_b[o]
    // final h is in hb[0] (t=127 wrote NXT=0), swizzled; rows 0..7 valid
    if (tid < kRows * 12) {
        int b = tid / 12, rem = tid % 12;
        int o = rem >> 2, q4 = rem & 3;
        float s = 0.f;
        const float* wrow = final_w + o * kState;
#pragma unroll 8
        for (int j = q4 * 32; j < q4 * 32 + 32; ++j) {
            uint16_t hval = hb[0][b][((j >> 3) ^ b) * 8 + (j & 7)];
            s += bf2f(hval) * wrow[j];
        }
        partial[b][o][q4] = s;
    }
    __syncthreads();
    if (tid < kRows * 3) {
        int b = tid / 3, o = tid % 3;
        float s = partial[b][o][0] + partial[b][o][1] +
                  partial[b][o][2] + partial[b][o][3] + final_b[o];
        out[(b0 + b) * 3 + o] = s;
    }
}

extern "C" void kernel_launch(void* const* d_in, const int* in_sizes, int n_in,
                              void* d_out, int out_size, void* d_ws, size_t ws_size,
                              hipStream_t stream) {
    const int*   ids        = (const int*)d_in[0];
    const float* embed      = (const float*)d_in[1];
    const float* whx_w      = (const float*)d_in[2];
    const float* whx_b      = (const float*)d_in[3];
    const float* init_state = (const float*)d_in[4];
    const float* final_w    = (const float*)d_in[5];
    const float* final_b    = (const float*)d_in[6];
    float*       out        = (float*)d_out;
    uint16_t*    wbf        = (uint16_t*)d_ws;                         // 320 KiB
    float*       zx         = (float*)((char*)d_ws + (size_t)kWElems * 2); // 83.9 MB

    convert_weights_kernel<<<kWElems / 4 / 256, 256, 0, stream>>>(whx_w, wbf);
    zx_gemm_kernel<<<kNTot / 64, 256, 0, stream>>>(wbf, embed, ids, whx_b, zx);
    tree_lstm_kernel<<<kBlocks, kThreads, 0, stream>>>(
        wbf, zx, embed, ids, init_state, final_w, final_b, out);
}

// Round 8
// 310.999 us; speedup vs baseline: 1.0057x; 1.0057x over previous
//
#include <hip/hip_runtime.h>
#include <stdint.h>

// Tree-LSTM scan: B=256, L=128, STATE=128, INIT=256, Z=5*128=640. fp32 I/O.
// Pipeline:
//  (0) whx_w fp32->bf16 into d_ws (full 640x256).
//  (1) zx_gemm: Zx[t*256+b][640] = W_x @ embed[ids[b,t]][0:128] + bias, fp32,
//      full-GPU MFMA GEMM with fused gather+bias, swapped operands (A=W,B=X)
//      -> per-lane float4 NONTEMPORAL stores.
//  (2) scan: 32 blocks x 512 threads, 8 batch rows/block, mirrored MFMA
//      B-cols, h LDS XOR-swizzled, raw v_exp_f32 gates, lgkmcnt-only
//      barrier. NEW (R8): W_h fragments are FORCED register-resident.
//      R0-R7 all had VGPR_Count=88 < the 80 VGPRs wf alone needs -- the
//      compiler was rematerializing all 20 weight-fragment global loads
//      INSIDE every step (and its vmcnt wait for them also drained the
//      t+1 Zx prefetch, oldest-first). The empty asm "+v" pin at each
//      iteration top makes wf loop-carried (cannot remat across an opaque
//      redefine); amdgpu_waves_per_eu(2,2) raises the VGPR cap to 256
//      (~190 live, 2 waves/SIMD unchanged).

constexpr int kL      = 128;
constexpr int kState  = 128;
constexpr int kInit   = 256;
constexpr int kRows   = 8;                      // batch rows per scan block
constexpr int kBlocks = 32;
constexpr int kThreads= 512;
constexpr int kWElems = 5 * kState * kInit;     // 163840 (320 KiB bf16)
constexpr int kNTot   = 256 * kL;               // 32768 (t,b) rows
constexpr int kZxCols = 5 * kState;             // 640

typedef __attribute__((ext_vector_type(8))) short short8;    // MFMA A/B frag
typedef __attribute__((ext_vector_type(4))) short short4v;
typedef __attribute__((ext_vector_type(4))) float floatx4;   // MFMA C/D frag

__device__ __forceinline__ uint16_t f2bf(float f) {
    union { float f; uint32_t i; } v; v.f = f;
    return (uint16_t)((v.i + 0x7FFFu + ((v.i >> 16) & 1u)) >> 16);  // RNE
}
__device__ __forceinline__ float bf2f(uint16_t u) {
    union { uint32_t i; float f; } v; v.i = ((uint32_t)u) << 16; return v.f;
}
__device__ __forceinline__ float fexp2(float x) {
    return __builtin_amdgcn_exp2f(x);           // raw v_exp_f32
}
// Raw barrier: order LDS (h publish) but let VMEM prefetch stay in flight.
__device__ __forceinline__ void bar_lds_only() {
    asm volatile("s_waitcnt lgkmcnt(0)" ::: "memory");
    __builtin_amdgcn_sched_barrier(0);
    __builtin_amdgcn_s_barrier();
    __builtin_amdgcn_sched_barrier(0);
}

// ---- kernel 0: whx_w fp32 -> bf16 (row-major 640x256) ----
__global__ __launch_bounds__(256)
void convert_weights_kernel(const float* __restrict__ wsrc,
                            uint16_t* __restrict__ wdst) {
    int i = blockIdx.x * 256 + threadIdx.x;          // float4 index
    float4 v = ((const float4*)wsrc)[i];
    uint16_t q[4] = { f2bf(v.x), f2bf(v.y), f2bf(v.z), f2bf(v.w) };
    ((short4v*)wdst)[i] = *(short4v*)q;
}

// ---- kernel 1: Zx[n][j] = sum_k W[j][128+k]*embed[id(n)][k] + bias[j] ----
// Swapped operands: A = W_x rows (lane l15 = j mod 16), B = X (lane l15 = n
// mod 16, k = quad*8+e). D: row = quad*4+r = j-local (consecutive!), col =
// l15 = n -> per-lane float4 nt store zx[n0+l15][jf*16+quad*4 .. +3].
__global__ __launch_bounds__(256)
void zx_gemm_kernel(const uint16_t* __restrict__ wbf,
                    const float* __restrict__ embed,
                    const int* __restrict__ ids,
                    const float* __restrict__ whx_b,
                    float* __restrict__ zx)
{
    const int wv   = threadIdx.x >> 6;
    const int lane = threadIdx.x & 63;
    const int l15  = lane & 15;
    const int quad = lane >> 4;
    const int n0   = (blockIdx.x * 4 + wv) * 16;
    const int T    = n0 >> 8;                  // timestep
    const int B    = (n0 & 255) + l15;         // batch row (n col) for lane
    const int id   = ids[B * kL + T];

    // B-frag: X[k, n] -- lane's own embed row, bf16-converted
    short8 xf[4];
    const float* xr = embed + (size_t)id * kInit;   // right_h = cols 0..127
#pragma unroll
    for (int kk = 0; kk < 4; ++kk) {
        float4 v0 = *(const float4*)(xr + kk * 32 + quad * 8);
        float4 v1 = *(const float4*)(xr + kk * 32 + quad * 8 + 4);
        uint16_t q[8] = { f2bf(v0.x), f2bf(v0.y), f2bf(v0.z), f2bf(v0.w),
                          f2bf(v1.x), f2bf(v1.y), f2bf(v1.z), f2bf(v1.w) };
        xf[kk] = *(short8*)q;
    }

    float* zrow = zx + (size_t)(n0 + l15) * kZxCols;
#pragma unroll 4
    for (int jf = 0; jf < 40; ++jf) {
        // A-frag: W rows j = jf*16 + l15, x-part cols
        const uint16_t* wr = wbf + (size_t)(jf * 16 + l15) * kInit + kState;
        // bias for the 4 owned j rows (quad*4 .. +3), same for all l15
        floatx4 acc = *(const floatx4*)(whx_b + jf * 16 + quad * 4);
#pragma unroll
        for (int kk = 0; kk < 4; ++kk) {
            short8 wa = *(const short8*)(wr + kk * 32 + quad * 8);
            acc = __builtin_amdgcn_mfma_f32_16x16x32_bf16(wa, xf[kk], acc, 0, 0, 0);
        }
        __builtin_nontemporal_store(acc, (floatx4*)(zrow + jf * 16 + quad * 4));
    }
}

// ---- kernel 2: the scan (h-recurrence only, K=128) ----
__global__ __launch_bounds__(kThreads)
__attribute__((amdgpu_waves_per_eu(2, 2)))
void tree_lstm_kernel(const uint16_t* __restrict__ wbf,
                      const float* __restrict__ zx,
                      const float* __restrict__ embed,
                      const int* __restrict__ ids,
                      const float* __restrict__ init_state,
                      const float* __restrict__ final_w,
                      const float* __restrict__ final_b,
                      float* __restrict__ out)
{
    // swizzled: element (row, col) lives at [row][ ((col>>3)^row)*8 + (col&7) ]
    // rows 8..15 mirror rows 0..7 (dual-write) -> MFMA D cols 8..15 mirror.
    __shared__ alignas(16) uint16_t hb[2][16][kState];      // 8 KB  (h)
    __shared__ int ids_l[kL][kRows];                        // 4 KB, [t][b]
    __shared__ float partial[kRows][3][4];
    // >80 KiB total => exactly 1 workgroup/CU.
    __shared__ float lds_force_pad[18432];                  // 72 KiB

    const int tid  = threadIdx.x;
    const int w    = tid >> 6;        // wave 0..7 -> j-slice [16w,16w+16)
    const int lane = tid & 63;
    const int l15  = lane & 15;       // MFMA D col (batch, mirrored over 8)
    const int quad = lane >> 4;       // 0..3
    const int b0   = blockIdx.x * kRows;
    const int j0   = w * 16 + quad * 4;   // 4 consecutive j (MFMA D rows)
    const int bl   = l15 & 7;             // owned batch row
    const bool hig = l15 >= 8;            // owns r-slots {2,3}
    const int jp   = j0 + (hig ? 2 : 0);  // first owned j

    if (__builtin_expect(ids[0] < 0, 0)) {      // never true; keeps pad alive
        volatile float* vp = lds_force_pad;
        vp[tid] = (float)tid;
        float v = vp[(tid * 7) & 16383];
        if (v < -1.0e30f) out[0] = v;
    }

    // stage ids transposed [t][b]
    for (int i = tid; i < kL * kRows; i += kThreads)
        ids_l[i >> 3][i & 7] = ids[(b0 + (i & 7)) * kL + (i >> 3)];

    // A-frags, h-part only (cols 0..127): 80 VGPRs, pinned resident below
    short8 wf[5][4];
#pragma unroll
    for (int g = 0; g < 5; ++g) {
        const uint16_t* wrow = wbf + (size_t)(g * 128 + w * 16 + l15) * kInit;
#pragma unroll
        for (int kk = 0; kk < 4; ++kk)
            wf[g][kk] = *(const short8*)(wrow + kk * 32 + quad * 8);
    }

    // h0 (bf16, swizzled into hb[0]; all 16 rows incl. mirrors get identical
    // broadcast values) and c0 (fp32 regs for the 2 owned slots)
    const int g8   = 2 * w + (quad >> 1);                // col group of j0/jp
    const int hoff = (g8 ^ l15) * 8 + (quad & 1) * 4;    // h0 write offset
    float c_reg[2];
    {
        uint16_t h0[4];
#pragma unroll
        for (int r = 0; r < 4; ++r)
            h0[r] = f2bf(init_state[j0 + r]);
        c_reg[0] = init_state[128 + jp];
        c_reg[1] = init_state[128 + jp + 1];
        *(short4v*)&hb[0][l15][hoff] = *(short4v*)h0;
    }
    __syncthreads();   // prologue barrier: ids_l + h0 visible (full drain ok)

    // per-step h write: 2 bf16 (4 B) to row bl AND mirror row bl+8
    const int eoff  = (quad & 1) * 4 + (hig ? 2 : 0);    // jp & 7
    const int wlo   = (g8 ^ bl) * 8 + eoff;
    const int whi   = ((g8 ^ bl) ^ 8) * 8 + eoff;

    // register double-buffer for Zx (acc init; row clamped to bl so mirror
    // cols get duplicates) and right_c (2 owned values); literal-indexed
    floatx4 zbuf[2][5];
    float2  rbuf[2];
    {
        const float* zr = zx + ((size_t)b0 + bl) * kZxCols + j0;   // t=0
#pragma unroll
        for (int g = 0; g < 5; ++g)
            zbuf[0][g] = *(const floatx4*)(zr + g * 128);
        int id0 = ids_l[0][bl];
        rbuf[0] = *(const float2*)(embed + (size_t)id0 * kInit + kState + jp);
    }

    const float K1 = 1.442695041f;   // log2(e)
    const float K2 = 2.885390082f;   // 2*log2(e)

    // Opaque redefine of every wf frag: compiler must keep them in VGPRs
    // across iterations (cannot rematerialize the global loads).
#define PIN_WF()                                                               \
    asm volatile(""                                                            \
        : "+v"(wf[0][0]), "+v"(wf[0][1]), "+v"(wf[0][2]), "+v"(wf[0][3]),      \
          "+v"(wf[1][0]), "+v"(wf[1][1]), "+v"(wf[1][2]), "+v"(wf[1][3]),      \
          "+v"(wf[2][0]), "+v"(wf[2][1]), "+v"(wf[2][2]), "+v"(wf[2][3]),      \
          "+v"(wf[3][0]), "+v"(wf[3][1]), "+v"(wf[3][2]), "+v"(wf[3][3]),      \
          "+v"(wf[4][0]), "+v"(wf[4][1]), "+v"(wf[4][2]), "+v"(wf[4][3]))

    // One gate cell. RL = literal r (0/1); select mirrors via cndmask.
    // fminf-only clamps: unclamped directions are safe (Inf -> rcp -> 0;
    // v_exp_f32 handles +-Inf inputs with the correct limits).
#define GATE_CELL(RL, RCV, HVOUT)                                              \
    {                                                                          \
        float ga = hig ? acc[0][RL + 2] : acc[0][RL];                          \
        float gi = hig ? acc[1][RL + 2] : acc[1][RL];                          \
        float g1 = hig ? acc[2][RL + 2] : acc[2][RL];                          \
        float g2 = hig ? acc[3][RL + 2] : acc[3][RL];                          \
        float go = hig ? acc[4][RL + 2] : acc[4][RL];                          \
        float a  = fminf(ga, 15.f);                                            \
        float f1 = fminf(g1, 30.f);                                            \
        float f2 = fminf(g2, 30.f);                                            \
        float Ea = fexp2(a * K2);                 /* e^{2a} */                 \
        float Ei = fexp2(-gi * K1);               /* e^{-i} */                 \
        float P  = (Ea - 1.0f) *                                               \
            __builtin_amdgcn_rcpf((Ea + 1.0f) * (1.0f + Ei));                  \
        float E1 = fexp2(f1 * K1), E2 = fexp2(f2 * K1);                        \
        float lc = c_reg[RL], rc = (RCV);                                      \
        float num = E1 * (1.0f + E2) * lc + E2 * (1.0f + E1) * rc;             \
        float Q  = num * __builtin_amdgcn_rcpf((1.0f + E1) * (1.0f + E2));     \
        float c  = P + Q;                                                      \
        c_reg[RL] = c;                                                         \
        float Eo = fexp2(-go * K1);                                            \
        float cc = fminf(c, 15.f);                                             \
        float Ec = fexp2(cc * K2);                                             \
        float h  = (Ec - 1.0f) *                                               \
            __builtin_amdgcn_rcpf((1.0f + Eo) * (Ec + 1.0f));                  \
        HVOUT = f2bf(h);                                                       \
    }

#define LSTM_STEP(T, CUR, NXT)                                                 \
    {                                                                          \
        /* prefetch t+1; stays IN FLIGHT across the raw barrier below */       \
        int tn = (T) + 1; if (tn >= kL) tn = kL - 1;                           \
        const float* zr = zx + ((size_t)tn * 256 + b0 + bl) * kZxCols + j0;    \
        _Pragma("unroll")                                                      \
        for (int g = 0; g < 5; ++g)                                            \
            zbuf[NXT][g] = *(const floatx4*)(zr + g * 128);                    \
        int idn = ids_l[tn][bl];                                               \
        rbuf[NXT] = *(const float2*)(embed + (size_t)idn * kInit + kState + jp); \
        /* acc init = Zx (x-part + bias), then h-part MFMAs */                 \
        floatx4 acc[5];                                                        \
        _Pragma("unroll")                                                      \
        for (int g = 0; g < 5; ++g) acc[g] = zbuf[CUR][g];                     \
        const uint16_t* hrow = &hb[CUR][l15][0];                               \
        _Pragma("unroll")                                                      \
        for (int kk = 0; kk < 4; ++kk) {                                       \
            short8 xf = *(const short8*)(hrow + ((kk * 4 + quad) ^ l15) * 8);  \
            _Pragma("unroll")                                                  \
            for (int g = 0; g < 5; ++g)                                        \
                acc[g] = __builtin_amdgcn_mfma_f32_16x16x32_bf16(              \
                    wf[g][kk], xf, acc[g], 0, 0, 0);                           \
        }                                                                      \
        uint16_t hv0, hv1;                                                     \
        GATE_CELL(0, rbuf[CUR].x, hv0)                                         \
        GATE_CELL(1, rbuf[CUR].y, hv1)                                         \
        uint32_t hp = (uint32_t)hv0 | ((uint32_t)hv1 << 16);                   \
        *(uint32_t*)&hb[NXT][bl][wlo]     = hp;                                \
        *(uint32_t*)&hb[NXT][bl + 8][whi] = hp;                                \
        bar_lds_only();   /* lgkmcnt(0)+s_barrier: h published, VMEM flows */  \
    }

#pragma unroll 1
    for (int t2 = 0; t2 < kL; t2 += 2) {
        PIN_WF();
        LSTM_STEP(t2, 0, 1)
        LSTM_STEP(t2 + 1, 1, 0)
    }
#undef LSTM_STEP
#undef GATE_CELL
#undef PIN_WF

    // final: out[b][o] = sum_j h[b][j]*final_w[o][j] + final_b[o]
    // final h is in hb[0] (t=127 wrote NXT=0), swizzled; rows 0..7 valid
    if (tid < kRows * 12) {
        int b = tid / 12, rem = tid % 12;
        int o = rem >> 2, q4 = rem & 3;
        float s = 0.f;
        const float* wrow = final_w + o * kState;
#pragma unroll 8
        for (int j = q4 * 32; j < q4 * 32 + 32; ++j) {
            uint16_t hval = hb[0][b][((j >> 3) ^ b) * 8 + (j & 7)];
            s += bf2f(hval) * wrow[j];
        }
        partial[b][o][q4] = s;
    }
    __syncthreads();
    if (tid < kRows * 3) {
        int b = tid / 3, o = tid % 3;
        float s = partial[b][o][0] + partial[b][o][1] +
                  partial[b][o][2] + partial[b][o][3] + final_b[o];
        out[(b0 + b) * 3 + o] = s;
    }
}

extern "C" void kernel_launch(void* const* d_in, const int* in_sizes, int n_in,
                              void* d_out, int out_size, void* d_ws, size_t ws_size,
                              hipStream_t stream) {
    const int*   ids        = (const int*)d_in[0];
    const float* embed      = (const float*)d_in[1];
    const float* whx_w      = (const float*)d_in[2];
    const float* whx_b      = (const float*)d_in[3];
    const float* init_state = (const float*)d_in[4];
    const float* final_w    = (const float*)d_in[5];
    const float* final_b    = (const float*)d_in[6];
    float*       out        = (float*)d_out;
    uint16_t*    wbf        = (uint16_t*)d_ws;                         // 320 KiB
    float*       zx         = (float*)((char*)d_ws + (size_t)kWElems * 2); // 83.9 MB

    convert_weights_kernel<<<kWElems / 4 / 256, 256, 0, stream>>>(whx_w, wbf);
    zx_gemm_kernel<<<kNTot / 64, 256, 0, stream>>>(wbf, embed, ids, whx_b, zx);
    tree_lstm_kernel<<<kBlocks, kThreads, 0, stream>>>(
        wbf, zx, embed, ids, init_state, final_w, final_b, out);
}

// Round 10
// 249.335 us; speedup vs baseline: 1.2545x; 1.2473x over previous
//
#include <hip/hip_runtime.h>
#include <stdint.h>

// Tree-LSTM scan: B=256, L=128, STATE=128, INIT=256, Z=5*128=640. fp32 I/O.
// Pipeline:
//  (0) whx_w fp32->bf16 into d_ws (full 640x256).
//  (1) zx_gemm: Zx[t*256+b][640] = W_x @ embed[ids[b,t]][0:128] + bias, fp32,
//      full-GPU MFMA GEMM, swapped operands, float4 nontemporal stores.
//  (2) scan: 32 blocks x 512 threads, 8 batch rows/block, mirrored MFMA
//      B-cols, W_h register-resident, h LDS XOR-swizzled, raw v_exp_f32.
//      R9: Zx and right_c flow through LDS via global_load_lds, staged
//      2 STEPS AHEAD into triple buffers, counted s_waitcnt vmcnt(6)
//      before the per-step raw barrier (never 0 in the loop). Each
//      step's vmcnt(6) drains exactly the next step's 6 tile loads;
//      barrier makes them visible to all waves. Writes always target
//      the slot consumed in the PREVIOUS step (race-free).
//      R10 FIX: global_load_lds's imm offset applies to BOTH the global
//      and LDS address (LLVM IntrinsicsAMDGPU.td) -- R9 pre-offset the
//      LDS base AND passed the imm, double-counting the LDS side
//      (stale [1024,2048) in every Zx row -> NaN). Now the un-offset
//      slot base is passed and the IMM advances both sides together.

constexpr int kL      = 128;
constexpr int kState  = 128;
constexpr int kInit   = 256;
constexpr int kRows   = 8;                      // batch rows per scan block
constexpr int kBlocks = 32;
constexpr int kThreads= 512;
constexpr int kWElems = 5 * kState * kInit;     // 163840 (320 KiB bf16)
constexpr int kNTot   = 256 * kL;               // 32768 (t,b) rows
constexpr int kZxCols = 5 * kState;             // 640
constexpr int kZRowB  = 2592;                   // LDS zx row stride (bytes)
constexpr int kRRowB  = 520;                    // LDS rc row stride (bytes)
constexpr int kZStep  = 256 * kZxCols * 4;      // 655360 B per t in global zx

typedef __attribute__((ext_vector_type(8))) short short8;    // MFMA A/B frag
typedef __attribute__((ext_vector_type(4))) short short4v;
typedef __attribute__((ext_vector_type(4))) float floatx4;   // MFMA C/D frag

__device__ __forceinline__ uint16_t f2bf(float f) {
    union { float f; uint32_t i; } v; v.f = f;
    return (uint16_t)((v.i + 0x7FFFu + ((v.i >> 16) & 1u)) >> 16);  // RNE
}
__device__ __forceinline__ float bf2f(uint16_t u) {
    union { uint32_t i; float f; } v; v.i = ((uint32_t)u) << 16; return v.f;
}
__device__ __forceinline__ float fexp2(float x) {
    return __builtin_amdgcn_exp2f(x);           // raw v_exp_f32
}

// async global->LDS: dest = wave-uniform base + IMM + lane*size;
// src = per-lane addr + IMM. (IMM applies to BOTH addresses.)
#define GL16(SRC, LDSP, IMM) __builtin_amdgcn_global_load_lds(               \
    (const __attribute__((address_space(1))) uint32_t*)(uintptr_t)(SRC),     \
    (__attribute__((address_space(3))) uint32_t*)(uintptr_t)(LDSP), 16, (IMM), 0)
#define GL4(SRC, LDSP, IMM) __builtin_amdgcn_global_load_lds(                \
    (const __attribute__((address_space(1))) uint32_t*)(uintptr_t)(SRC),     \
    (__attribute__((address_space(3))) uint32_t*)(uintptr_t)(LDSP), 4, (IMM), 0)

// ---- kernel 0: whx_w fp32 -> bf16 (row-major 640x256) ----
__global__ __launch_bounds__(256)
void convert_weights_kernel(const float* __restrict__ wsrc,
                            uint16_t* __restrict__ wdst) {
    int i = blockIdx.x * 256 + threadIdx.x;          // float4 index
    float4 v = ((const float4*)wsrc)[i];
    uint16_t q[4] = { f2bf(v.x), f2bf(v.y), f2bf(v.z), f2bf(v.w) };
    ((short4v*)wdst)[i] = *(short4v*)q;
}

// ---- kernel 1: Zx[n][j] = sum_k W[j][128+k]*embed[id(n)][k] + bias[j] ----
__global__ __launch_bounds__(256)
void zx_gemm_kernel(const uint16_t* __restrict__ wbf,
                    const float* __restrict__ embed,
                    const int* __restrict__ ids,
                    const float* __restrict__ whx_b,
                    float* __restrict__ zx)
{
    const int wv   = threadIdx.x >> 6;
    const int lane = threadIdx.x & 63;
    const int l15  = lane & 15;
    const int quad = lane >> 4;
    const int n0   = (blockIdx.x * 4 + wv) * 16;
    const int T    = n0 >> 8;                  // timestep
    const int B    = (n0 & 255) + l15;         // batch row (n col) for lane
    const int id   = ids[B * kL + T];

    short8 xf[4];
    const float* xr = embed + (size_t)id * kInit;   // right_h = cols 0..127
#pragma unroll
    for (int kk = 0; kk < 4; ++kk) {
        float4 v0 = *(const float4*)(xr + kk * 32 + quad * 8);
        float4 v1 = *(const float4*)(xr + kk * 32 + quad * 8 + 4);
        uint16_t q[8] = { f2bf(v0.x), f2bf(v0.y), f2bf(v0.z), f2bf(v0.w),
                          f2bf(v1.x), f2bf(v1.y), f2bf(v1.z), f2bf(v1.w) };
        xf[kk] = *(short8*)q;
    }

    float* zrow = zx + (size_t)(n0 + l15) * kZxCols;
#pragma unroll 4
    for (int jf = 0; jf < 40; ++jf) {
        const uint16_t* wr = wbf + (size_t)(jf * 16 + l15) * kInit + kState;
        floatx4 acc = *(const floatx4*)(whx_b + jf * 16 + quad * 4);
#pragma unroll
        for (int kk = 0; kk < 4; ++kk) {
            short8 wa = *(const short8*)(wr + kk * 32 + quad * 8);
            acc = __builtin_amdgcn_mfma_f32_16x16x32_bf16(wa, xf[kk], acc, 0, 0, 0);
        }
        __builtin_nontemporal_store(acc, (floatx4*)(zrow + jf * 16 + quad * 4));
    }
}

// ---- kernel 2: the scan (h-recurrence only, K=128) ----
__global__ __launch_bounds__(kThreads)
__attribute__((amdgpu_waves_per_eu(1, 2)))
void tree_lstm_kernel(const uint16_t* __restrict__ wbf,
                      const float* __restrict__ zx,
                      const float* __restrict__ embed,
                      const int* __restrict__ ids,
                      const float* __restrict__ init_state,
                      const float* __restrict__ final_w,
                      const float* __restrict__ final_b,
                      float* __restrict__ out)
{
    // h swizzle: (row,col) at [row][ ((col>>3)^row)*8 + (col&7) ]; rows 8..15
    // mirror rows 0..7. Zx/rc tiles: triple-buffered, staged 2 steps ahead.
    __shared__ alignas(16) uint8_t  zxt[3][kRows][kZRowB];  // 62208 B
    __shared__ alignas(8)  uint8_t  rct[3][kRows][kRRowB];  // 12480 B
    __shared__ alignas(16) uint16_t hb[2][16][kState];      //  8192 B
    __shared__ float partial[kRows][3][4];                  //   384 B
    // total 83264 B > 80 KiB => exactly 1 workgroup/CU.

    const int tid  = threadIdx.x;
    const int w    = tid >> 6;        // wave 0..7 -> j-slice [16w,16w+16)
    const int lane = tid & 63;
    const int l15  = lane & 15;       // MFMA D col (batch, mirrored over 8)
    const int quad = lane >> 4;       // 0..3
    const int b0   = blockIdx.x * kRows;
    const int j0   = w * 16 + quad * 4;   // 4 consecutive j (MFMA D rows)
    const int bl   = l15 & 7;             // owned batch row
    const bool hig = l15 >= 8;            // owns r-slots {2,3}
    const int jp   = j0 + (hig ? 2 : 0);  // first owned j
    const int wu   = __builtin_amdgcn_readfirstlane(w);
    const int irow = (b0 + wu) * kL;      // this wave's ids row base

    // lane-const LDS read offsets
    const int zx_rd = bl * kZRowB + j0 * 4;
    const int rc_rd = bl * kRRowB + jp * 4;

    // rotating tile pointers: (A,B,C) = slots (t%3,(t+1)%3,(t+2)%3)
    uint8_t* zA = &zxt[0][0][0]; uint8_t* zB = &zxt[1][0][0]; uint8_t* zC = &zxt[2][0][0];
    uint8_t* rA = &rct[0][0][0]; uint8_t* rB = &rct[1][0][0]; uint8_t* rC = &rct[2][0][0];

    // per-lane global srcs for zx staging (start at t=0, wave's own row)
    const char* zs16 = (const char*)zx + (size_t)(b0 + wu) * (kZxCols * 4) + lane * 16;
    const char* zs4  = (const char*)zx + (size_t)(b0 + wu) * (kZxCols * 4) + 2048 + lane * 4;

    // register-resident A-frags, h-part only (cols 0..127): 80 VGPRs
    short8 wf[5][4];
#pragma unroll
    for (int g = 0; g < 5; ++g) {
        const uint16_t* wrow = wbf + (size_t)(g * 128 + w * 16 + l15) * kInit;
#pragma unroll
        for (int kk = 0; kk < 4; ++kk)
            wf[g][kk] = *(const short8*)(wrow + kk * 32 + quad * 8);
    }

    // h0 (bf16, swizzled into hb[0]) and c0 (fp32 regs for the 2 owned slots)
    const int g8   = 2 * w + (quad >> 1);                // col group of j0/jp
    const int hoff = (g8 ^ l15) * 8 + (quad & 1) * 4;    // h0 write offset
    float c_reg[2];
    {
        uint16_t h0[4];
#pragma unroll
        for (int r = 0; r < 4; ++r)
            h0[r] = f2bf(init_state[j0 + r]);
        c_reg[0] = init_state[128 + jp];
        c_reg[1] = init_state[128 + jp + 1];
        *(short4v*)&hb[0][l15][hoff] = *(short4v*)h0;
    }

    // prologue staging: t=0 -> (zA,rA), t=1 -> (zB,rB).
    // IMM advances BOTH global src and LDS dest together.
    {
        uint8_t* zb0 = zA + w * kZRowB;
        GL16(zs16, zb0, 0);  GL16(zs16, zb0, 1024);
        GL4(zs4, zb0 + 2048, 0); GL4(zs4, zb0 + 2048, 256);
        int id0 = ids[irow + 0];
        const char* rs0 = (const char*)embed + (size_t)id0 * 1024 + 512 + lane * 4;
        uint8_t* rb0 = rA + w * kRRowB;
        GL4(rs0, rb0, 0); GL4(rs0, rb0, 256);
        zs16 += kZStep; zs4 += kZStep;
        uint8_t* zb1 = zB + w * kZRowB;
        GL16(zs16, zb1, 0);  GL16(zs16, zb1, 1024);
        GL4(zs4, zb1 + 2048, 0); GL4(zs4, zb1 + 2048, 256);
        int id1 = ids[irow + 1];
        const char* rs1 = (const char*)embed + (size_t)id1 * 1024 + 512 + lane * 4;
        uint8_t* rb1 = rB + w * kRRowB;
        GL4(rs1, rb1, 0); GL4(rs1, rb1, 256);
        zs16 += kZStep; zs4 += kZStep;           // now points at t=2
    }
    __syncthreads();   // full drain: h0 + tiles t=0,1 resident

    // per-step h write: 2 bf16 (4 B) to row bl AND mirror row bl+8
    const int eoff  = (quad & 1) * 4 + (hig ? 2 : 0);    // jp & 7
    const int wlo   = (g8 ^ bl) * 8 + eoff;
    const int whi   = ((g8 ^ bl) ^ 8) * 8 + eoff;

    const float K1 = 1.442695041f;   // log2(e)
    const float K2 = 2.885390082f;   // 2*log2(e)

    // fminf-only clamps: unclamped directions safe (Inf -> rcp -> 0).
#define GATE_CELL(RL, RCV, HVOUT)                                              \
    {                                                                          \
        float ga = hig ? acc[0][RL + 2] : acc[0][RL];                          \
        float gi = hig ? acc[1][RL + 2] : acc[1][RL];                          \
        float g1 = hig ? acc[2][RL + 2] : acc[2][RL];                          \
        float g2 = hig ? acc[3][RL + 2] : acc[3][RL];                          \
        float go = hig ? acc[4][RL + 2] : acc[4][RL];                          \
        float a  = fminf(ga, 15.f);                                            \
        float f1 = fminf(g1, 30.f);                                            \
        float f2 = fminf(g2, 30.f);                                            \
        float Ea = fexp2(a * K2);                 /* e^{2a} */                 \
        float Ei = fexp2(-gi * K1);               /* e^{-i} */                 \
        float P  = (Ea - 1.0f) *                                               \
            __builtin_amdgcn_rcpf((Ea + 1.0f) * (1.0f + Ei));                  \
        float E1 = fexp2(f1 * K1), E2 = fexp2(f2 * K1);                        \
        float lc = c_reg[RL], rc = (RCV);                                      \
        float num = E1 * (1.0f + E2) * lc + E2 * (1.0f + E1) * rc;             \
        float Q  = num * __builtin_amdgcn_rcpf((1.0f + E1) * (1.0f + E2));     \
        float c  = P + Q;                                                      \
        c_reg[RL] = c;                                                         \
        float Eo = fexp2(-go * K1);                                            \
        float cc = fminf(c, 15.f);                                             \
        float Ec = fexp2(cc * K2);                                             \
        float h  = (Ec - 1.0f) *                                               \
            __builtin_amdgcn_rcpf((1.0f + Eo) * (Ec + 1.0f));                  \
        HVOUT = f2bf(h);                                                       \
    }

#define LSTM_STEP(T, CUR, NXT, ZRD, RRD, ZWR, RWR)                             \
    {                                                                          \
        /* 1. tile ds_reads FIRST (outstanding vmem = t+1's, already landed)*/ \
        const uint8_t* zrow = (ZRD) + zx_rd;                                   \
        floatx4 acc[5];                                                        \
        _Pragma("unroll")                                                      \
        for (int g = 0; g < 5; ++g)                                            \
            acc[g] = *(const floatx4*)(zrow + g * 512);                        \
        float2 rcv = *(const float2*)((RRD) + rc_rd);                          \
        const uint16_t* hrow = &hb[CUR][l15][0];                               \
        short8 xf0 = *(const short8*)(hrow + ((0 * 4 + quad) ^ l15) * 8);      \
        short8 xf1 = *(const short8*)(hrow + ((1 * 4 + quad) ^ l15) * 8);      \
        short8 xf2 = *(const short8*)(hrow + ((2 * 4 + quad) ^ l15) * 8);      \
        short8 xf3 = *(const short8*)(hrow + ((3 * 4 + quad) ^ l15) * 8);      \
        /* 2. issue t+2 staging (6 gloads; consumed 2 steps later) */          \
        int tn2 = (T) + 2; if (tn2 > kL - 1) tn2 = kL - 1;                     \
        uint8_t* zwb = (ZWR) + w * kZRowB;                                     \
        GL16(zs16, zwb, 0);                                                    \
        GL16(zs16, zwb, 1024);                                                 \
        GL4(zs4, zwb + 2048, 0);                                               \
        GL4(zs4, zwb + 2048, 256);                                             \
        int idn = ids[irow + tn2];                                             \
        const char* rsn = (const char*)embed + (size_t)idn * 1024 + 512        \
                          + lane * 4;                                          \
        uint8_t* rwb = (RWR) + w * kRRowB;                                     \
        GL4(rsn, rwb, 0);                                                      \
        GL4(rsn, rwb, 256);                                                    \
        size_t adv = ((T) + 3 <= kL - 1) ? (size_t)kZStep : 0;                 \
        zs16 += adv; zs4 += adv;                                               \
        /* 3. MFMA: acc += W_h * h */                                          \
        _Pragma("unroll")                                                      \
        for (int g = 0; g < 5; ++g)                                            \
            acc[g] = __builtin_amdgcn_mfma_f32_16x16x32_bf16(wf[g][0], xf0, acc[g], 0, 0, 0); \
        _Pragma("unroll")                                                      \
        for (int g = 0; g < 5; ++g)                                            \
            acc[g] = __builtin_amdgcn_mfma_f32_16x16x32_bf16(wf[g][1], xf1, acc[g], 0, 0, 0); \
        _Pragma("unroll")                                                      \
        for (int g = 0; g < 5; ++g)                                            \
            acc[g] = __builtin_amdgcn_mfma_f32_16x16x32_bf16(wf[g][2], xf2, acc[g], 0, 0, 0); \
        _Pragma("unroll")                                                      \
        for (int g = 0; g < 5; ++g)                                            \
            acc[g] = __builtin_amdgcn_mfma_f32_16x16x32_bf16(wf[g][3], xf3, acc[g], 0, 0, 0); \
        /* 4. gates + h publish */                                             \
        uint16_t hv0, hv1;                                                     \
        GATE_CELL(0, rcv.x, hv0)                                               \
        GATE_CELL(1, rcv.y, hv1)                                               \
        uint32_t hp = (uint32_t)hv0 | ((uint32_t)hv1 << 16);                   \
        *(uint32_t*)&hb[NXT][bl][wlo]     = hp;                                \
        *(uint32_t*)&hb[NXT][bl + 8][whi] = hp;                                \
        /* 5. counted drain: my t+1 loads done; t+2's 6 stay in flight */      \
        asm volatile("s_waitcnt vmcnt(6) lgkmcnt(0)" ::: "memory");            \
        __builtin_amdgcn_sched_barrier(0);                                     \
        __builtin_amdgcn_s_barrier();                                          \
        __builtin_amdgcn_sched_barrier(0);                                     \
    }

#pragma unroll 1
    for (int t2 = 0; t2 < kL; t2 += 2) {
        LSTM_STEP(t2,     0, 1, zA, rA, zC, rC)
        LSTM_STEP(t2 + 1, 1, 0, zB, rB, zA, rA)
        // slots advance by 2: (A,B,C) <- (C,A,B)
        uint8_t* tz = zA; zA = zC; zC = zB; zB = tz;
        uint8_t* tr = rA; rA = rC; rC = rB; rB = tr;
    }
#undef LSTM_STEP
#undef GATE_CELL

    // final: out[b][o] = sum_j h[b][j]*final_w[o][j] + final_b[o]
    // final h is in hb[0] (t=127 wrote NXT=0), swizzled; rows 0..7 valid
    if (tid < kRows * 12) {
        int b = tid / 12, rem = tid % 12;
        int o = rem >> 2, q4 = rem & 3;
        float s = 0.f;
        const float* wrow = final_w + o * kState;
#pragma unroll 8
        for (int j = q4 * 32; j < q4 * 32 + 32; ++j) {
            uint16_t hval = hb[0][b][((j >> 3) ^ b) * 8 + (j & 7)];
            s += bf2f(hval) * wrow[j];
        }
        partial[b][o][q4] = s;
    }
    __syncthreads();
    if (tid < kRows * 3) {
        int b = tid / 3, o = tid % 3;
        float s = partial[b][o][0] + partial[b][o][1] +
                  partial[b][o][2] + partial[b][o][3] + final_b[o];
        out[(b0 + b) * 3 + o] = s;
    }
}

extern "C" void kernel_launch(void* const* d_in, const int* in_sizes, int n_in,
                              void* d_out, int out_size, void* d_ws, size_t ws_size,
                              hipStream_t stream) {
    const int*   ids        = (const int*)d_in[0];
    const float* embed      = (const float*)d_in[1];
    const float* whx_w      = (const float*)d_in[2];
    const float* whx_b      = (const float*)d_in[3];
    const float* init_state = (const float*)d_in[4];
    const float* final_w    = (const float*)d_in[5];
    const float* final_b    = (const float*)d_in[6];
    float*       out        = (float*)d_out;
    uint16_t*    wbf        = (uint16_t*)d_ws;                         // 320 KiB
    float*       zx         = (float*)((char*)d_ws + (size_t)kWElems * 2); // 83.9 MB

    convert_weights_kernel<<<kWElems / 4 / 256, 256, 0, stream>>>(whx_w, wbf);
    zx_gemm_kernel<<<kNTot / 64, 256, 0, stream>>>(wbf, embed, ids, whx_b, zx);
    tree_lstm_kernel<<<kBlocks, kThreads, 0, stream>>>(
        wbf, zx, embed, ids, init_state, final_w, final_b, out);
}

// Round 12
// 242.594 us; speedup vs baseline: 1.2893x; 1.0278x over previous
//
#include <hip/hip_runtime.h>
#include <stdint.h>

// Tree-LSTM scan: B=256, L=128, STATE=128, INIT=256, Z=5*128=640. fp32 I/O.
// Pipeline (R10 structure, proven 249us; fusion abandoned after R3/R11 --
// intra-kernel producer->consumer needs cross-XCD L2 bypass the dispatch
// boundary gives for free):
//  (0) whx_w fp32->bf16 into d_ws (full 640x256).
//  (1) zx_gemm: Zx[t*256+b][640] = W_x @ embed[ids[b,t]][0:128] + bias, fp32.
//      R12: 32 n-rows per wave (2 MFMA tiles sharing every weight frag) --
//      halves the 327MB aggregate weight re-read that made the old version
//      instruction-bound (~100us vs ~25us roofline); unroll 8 deepens
//      store/load overlap. Per-output math bit-identical.
//  (2) scan: 32 blocks x 512 threads, 8 batch rows/block, mirrored MFMA
//      B-cols, W_h register-resident, h LDS XOR-swizzled, raw v_exp_f32,
//      LDS-staged Zx/rc via global_load_lds 2 steps ahead (triple buffer),
//      counted s_waitcnt vmcnt(6), one raw barrier per step. 115.8us.

constexpr int kL      = 128;
constexpr int kState  = 128;
constexpr int kInit   = 256;
constexpr int kRows   = 8;                      // batch rows per scan block
constexpr int kBlocks = 32;
constexpr int kThreads= 512;
constexpr int kWElems = 5 * kState * kInit;     // 163840 (320 KiB bf16)
constexpr int kNTot   = 256 * kL;               // 32768 (t,b) rows
constexpr int kZxCols = 5 * kState;             // 640
constexpr int kZRowB  = 2592;                   // LDS zx row stride (bytes)
constexpr int kRRowB  = 520;                    // LDS rc row stride (bytes)
constexpr int kZStep  = 256 * kZxCols * 4;      // 655360 B per t in global zx

typedef __attribute__((ext_vector_type(8))) short short8;    // MFMA A/B frag
typedef __attribute__((ext_vector_type(4))) short short4v;
typedef __attribute__((ext_vector_type(4))) float floatx4;   // MFMA C/D frag

__device__ __forceinline__ uint16_t f2bf(float f) {
    union { float f; uint32_t i; } v; v.f = f;
    return (uint16_t)((v.i + 0x7FFFu + ((v.i >> 16) & 1u)) >> 16);  // RNE
}
__device__ __forceinline__ float bf2f(uint16_t u) {
    union { uint32_t i; float f; } v; v.i = ((uint32_t)u) << 16; return v.f;
}
__device__ __forceinline__ float fexp2(float x) {
    return __builtin_amdgcn_exp2f(x);           // raw v_exp_f32
}

// async global->LDS: dest = wave-uniform base + IMM + lane*size;
// src = per-lane addr + IMM. (IMM applies to BOTH addresses.)
#define GL16(SRC, LDSP, IMM) __builtin_amdgcn_global_load_lds(               \
    (const __attribute__((address_space(1))) uint32_t*)(uintptr_t)(SRC),     \
    (__attribute__((address_space(3))) uint32_t*)(uintptr_t)(LDSP), 16, (IMM), 0)
#define GL4(SRC, LDSP, IMM) __builtin_amdgcn_global_load_lds(                \
    (const __attribute__((address_space(1))) uint32_t*)(uintptr_t)(SRC),     \
    (__attribute__((address_space(3))) uint32_t*)(uintptr_t)(LDSP), 4, (IMM), 0)

// ---- kernel 0: whx_w fp32 -> bf16 (row-major 640x256) ----
__global__ __launch_bounds__(256)
void convert_weights_kernel(const float* __restrict__ wsrc,
                            uint16_t* __restrict__ wdst) {
    int i = blockIdx.x * 256 + threadIdx.x;          // float4 index
    float4 v = ((const float4*)wsrc)[i];
    uint16_t q[4] = { f2bf(v.x), f2bf(v.y), f2bf(v.z), f2bf(v.w) };
    ((short4v*)wdst)[i] = *(short4v*)q;
}

// ---- kernel 1: Zx[n][j] = sum_k W[j][128+k]*embed[id(n)][k] + bias[j] ----
// A = W_x rows (l15 = j mod 16), B = X (l15 = n mod 16). D: row = quad*4+r
// = j-local, col = l15 = n -> per-lane float4 nt store.
// R12: TWO n-tiles per wave (rows n0+l15 and n0+16+l15) share each weight
// fragment -> half the weight traffic, 2 MFMAs per wa load.
__global__ __launch_bounds__(256)
void zx_gemm_kernel(const uint16_t* __restrict__ wbf,
                    const float* __restrict__ embed,
                    const int* __restrict__ ids,
                    const float* __restrict__ whx_b,
                    float* __restrict__ zx)
{
    const int wv   = threadIdx.x >> 6;
    const int lane = threadIdx.x & 63;
    const int l15  = lane & 15;
    const int quad = lane >> 4;
    const int n0   = (blockIdx.x * 4 + wv) * 32;   // 32 rows per wave
    const int T    = n0 >> 8;                  // timestep (n0+31 same T)
    const int B0   = (n0 & 255) + l15;         // tile-0 batch row
    const int id0  = ids[B0 * kL + T];
    const int id1  = ids[(B0 + 16) * kL + T];  // tile-1 batch row

    // B-frags: X[k, n] for both tiles, bf16-converted
    short8 xf0[4], xf1[4];
    const float* xr0 = embed + (size_t)id0 * kInit;   // cols 0..127
    const float* xr1 = embed + (size_t)id1 * kInit;
#pragma unroll
    for (int kk = 0; kk < 4; ++kk) {
        float4 a0 = *(const float4*)(xr0 + kk * 32 + quad * 8);
        float4 a1 = *(const float4*)(xr0 + kk * 32 + quad * 8 + 4);
        uint16_t qa[8] = { f2bf(a0.x), f2bf(a0.y), f2bf(a0.z), f2bf(a0.w),
                           f2bf(a1.x), f2bf(a1.y), f2bf(a1.z), f2bf(a1.w) };
        xf0[kk] = *(short8*)qa;
        float4 b0 = *(const float4*)(xr1 + kk * 32 + quad * 8);
        float4 b1 = *(const float4*)(xr1 + kk * 32 + quad * 8 + 4);
        uint16_t qb[8] = { f2bf(b0.x), f2bf(b0.y), f2bf(b0.z), f2bf(b0.w),
                           f2bf(b1.x), f2bf(b1.y), f2bf(b1.z), f2bf(b1.w) };
        xf1[kk] = *(short8*)qb;
    }

    float* zr0 = zx + (size_t)(n0 + l15) * kZxCols;
    float* zr1 = zx + (size_t)(n0 + 16 + l15) * kZxCols;
#pragma unroll 8
    for (int jf = 0; jf < 40; ++jf) {
        // A-frag: W rows j = jf*16 + l15, x-part cols (shared by both tiles)
        const uint16_t* wr = wbf + (size_t)(jf * 16 + l15) * kInit + kState;
        floatx4 bias = *(const floatx4*)(whx_b + jf * 16 + quad * 4);
        floatx4 acc0 = bias, acc1 = bias;
#pragma unroll
        for (int kk = 0; kk < 4; ++kk) {
            short8 wa = *(const short8*)(wr + kk * 32 + quad * 8);
            acc0 = __builtin_amdgcn_mfma_f32_16x16x32_bf16(wa, xf0[kk], acc0, 0, 0, 0);
            acc1 = __builtin_amdgcn_mfma_f32_16x16x32_bf16(wa, xf1[kk], acc1, 0, 0, 0);
        }
        __builtin_nontemporal_store(acc0, (floatx4*)(zr0 + jf * 16 + quad * 4));
        __builtin_nontemporal_store(acc1, (floatx4*)(zr1 + jf * 16 + quad * 4));
    }
}

// ---- kernel 2: the scan (h-recurrence only, K=128) ----
__global__ __launch_bounds__(kThreads)
__attribute__((amdgpu_waves_per_eu(1, 2)))
void tree_lstm_kernel(const uint16_t* __restrict__ wbf,
                      const float* __restrict__ zx,
                      const float* __restrict__ embed,
                      const int* __restrict__ ids,
                      const float* __restrict__ init_state,
                      const float* __restrict__ final_w,
                      const float* __restrict__ final_b,
                      float* __restrict__ out)
{
    // h swizzle: (row,col) at [row][ ((col>>3)^row)*8 + (col&7) ]; rows 8..15
    // mirror rows 0..7. Zx/rc tiles: triple-buffered, staged 2 steps ahead.
    __shared__ alignas(16) uint8_t  zxt[3][kRows][kZRowB];  // 62208 B
    __shared__ alignas(8)  uint8_t  rct[3][kRows][kRRowB];  // 12480 B
    __shared__ alignas(16) uint16_t hb[2][16][kState];      //  8192 B
    __shared__ float partial[kRows][3][4];                  //   384 B
    // total 83264 B > 80 KiB => exactly 1 workgroup/CU.

    const int tid  = threadIdx.x;
    const int w    = tid >> 6;        // wave 0..7 -> j-slice [16w,16w+16)
    const int lane = tid & 63;
    const int l15  = lane & 15;       // MFMA D col (batch, mirrored over 8)
    const int quad = lane >> 4;       // 0..3
    const int b0   = blockIdx.x * kRows;
    const int j0   = w * 16 + quad * 4;   // 4 consecutive j (MFMA D rows)
    const int bl   = l15 & 7;             // owned batch row
    const bool hig = l15 >= 8;            // owns r-slots {2,3}
    const int jp   = j0 + (hig ? 2 : 0);  // first owned j
    const int wu   = __builtin_amdgcn_readfirstlane(w);
    const int irow = (b0 + wu) * kL;      // this wave's ids row base

    // lane-const LDS read offsets
    const int zx_rd = bl * kZRowB + j0 * 4;
    const int rc_rd = bl * kRRowB + jp * 4;

    // rotating tile pointers: (A,B,C) = slots (t%3,(t+1)%3,(t+2)%3)
    uint8_t* zA = &zxt[0][0][0]; uint8_t* zB = &zxt[1][0][0]; uint8_t* zC = &zxt[2][0][0];
    uint8_t* rA = &rct[0][0][0]; uint8_t* rB = &rct[1][0][0]; uint8_t* rC = &rct[2][0][0];

    // per-lane global srcs for zx staging (start at t=0, wave's own row)
    const char* zs16 = (const char*)zx + (size_t)(b0 + wu) * (kZxCols * 4) + lane * 16;
    const char* zs4  = (const char*)zx + (size_t)(b0 + wu) * (kZxCols * 4) + 2048 + lane * 4;

    // register-resident A-frags, h-part only (cols 0..127): 80 VGPRs
    short8 wf[5][4];
#pragma unroll
    for (int g = 0; g < 5; ++g) {
        const uint16_t* wrow = wbf + (size_t)(g * 128 + w * 16 + l15) * kInit;
#pragma unroll
        for (int kk = 0; kk < 4; ++kk)
            wf[g][kk] = *(const short8*)(wrow + kk * 32 + quad * 8);
    }

    // h0 (bf16, swizzled into hb[0]) and c0 (fp32 regs for the 2 owned slots)
    const int g8   = 2 * w + (quad >> 1);                // col group of j0/jp
    const int hoff = (g8 ^ l15) * 8 + (quad & 1) * 4;    // h0 write offset
    float c_reg[2];
    {
        uint16_t h0[4];
#pragma unroll
        for (int r = 0; r < 4; ++r)
            h0[r] = f2bf(init_state[j0 + r]);
        c_reg[0] = init_state[128 + jp];
        c_reg[1] = init_state[128 + jp + 1];
        *(short4v*)&hb[0][l15][hoff] = *(short4v*)h0;
    }

    // prologue staging: t=0 -> (zA,rA), t=1 -> (zB,rB).
    // IMM advances BOTH global src and LDS dest together.
    {
        uint8_t* zb0 = zA + w * kZRowB;
        GL16(zs16, zb0, 0);  GL16(zs16, zb0, 1024);
        GL4(zs4, zb0 + 2048, 0); GL4(zs4, zb0 + 2048, 256);
        int id0 = ids[irow + 0];
        const char* rs0 = (const char*)embed + (size_t)id0 * 1024 + 512 + lane * 4;
        uint8_t* rb0 = rA + w * kRRowB;
        GL4(rs0, rb0, 0); GL4(rs0, rb0, 256);
        zs16 += kZStep; zs4 += kZStep;
        uint8_t* zb1 = zB + w * kZRowB;
        GL16(zs16, zb1, 0);  GL16(zs16, zb1, 1024);
        GL4(zs4, zb1 + 2048, 0); GL4(zs4, zb1 + 2048, 256);
        int id1 = ids[irow + 1];
        const char* rs1 = (const char*)embed + (size_t)id1 * 1024 + 512 + lane * 4;
        uint8_t* rb1 = rB + w * kRRowB;
        GL4(rs1, rb1, 0); GL4(rs1, rb1, 256);
        zs16 += kZStep; zs4 += kZStep;           // now points at t=2
    }
    __syncthreads();   // full drain: h0 + tiles t=0,1 resident

    // per-step h write: 2 bf16 (4 B) to row bl AND mirror row bl+8
    const int eoff  = (quad & 1) * 4 + (hig ? 2 : 0);    // jp & 7
    const int wlo   = (g8 ^ bl) * 8 + eoff;
    const int whi   = ((g8 ^ bl) ^ 8) * 8 + eoff;

    const float K1 = 1.442695041f;   // log2(e)
    const float K2 = 2.885390082f;   // 2*log2(e)

    // fminf-only clamps: unclamped directions safe (Inf -> rcp -> 0).
#define GATE_CELL(RL, RCV, HVOUT)                                              \
    {                                                                          \
        float ga = hig ? acc[0][RL + 2] : acc[0][RL];                          \
        float gi = hig ? acc[1][RL + 2] : acc[1][RL];                          \
        float g1 = hig ? acc[2][RL + 2] : acc[2][RL];                          \
        float g2 = hig ? acc[3][RL + 2] : acc[3][RL];                          \
        float go = hig ? acc[4][RL + 2] : acc[4][RL];                          \
        float a  = fminf(ga, 15.f);                                            \
        float f1 = fminf(g1, 30.f);                                            \
        float f2 = fminf(g2, 30.f);                                            \
        float Ea = fexp2(a * K2);                 /* e^{2a} */                 \
        float Ei = fexp2(-gi * K1);               /* e^{-i} */                 \
        float P  = (Ea - 1.0f) *                                               \
            __builtin_amdgcn_rcpf((Ea + 1.0f) * (1.0f + Ei));                  \
        float E1 = fexp2(f1 * K1), E2 = fexp2(f2 * K1);                        \
        float lc = c_reg[RL], rc = (RCV);                                      \
        float num = E1 * (1.0f + E2) * lc + E2 * (1.0f + E1) * rc;             \
        float Q  = num * __builtin_amdgcn_rcpf((1.0f + E1) * (1.0f + E2));     \
        float c  = P + Q;                                                      \
        c_reg[RL] = c;                                                         \
        float Eo = fexp2(-go * K1);                                            \
        float cc = fminf(c, 15.f);                                             \
        float Ec = fexp2(cc * K2);                                             \
        float h  = (Ec - 1.0f) *                                               \
            __builtin_amdgcn_rcpf((1.0f + Eo) * (Ec + 1.0f));                  \
        HVOUT = f2bf(h);                                                       \
    }

#define LSTM_STEP(T, CUR, NXT, ZRD, RRD, ZWR, RWR)                             \
    {                                                                          \
        /* 1. tile ds_reads FIRST (outstanding vmem = t+1's, already landed)*/ \
        const uint8_t* zrow = (ZRD) + zx_rd;                                   \
        floatx4 acc[5];                                                        \
        _Pragma("unroll")                                                      \
        for (int g = 0; g < 5; ++g)                                            \
            acc[g] = *(const floatx4*)(zrow + g * 512);                        \
        float2 rcv = *(const float2*)((RRD) + rc_rd);                          \
        const uint16_t* hrow = &hb[CUR][l15][0];                               \
        short8 xf0 = *(const short8*)(hrow + ((0 * 4 + quad) ^ l15) * 8);      \
        short8 xf1 = *(const short8*)(hrow + ((1 * 4 + quad) ^ l15) * 8);      \
        short8 xf2 = *(const short8*)(hrow + ((2 * 4 + quad) ^ l15) * 8);      \
        short8 xf3 = *(const short8*)(hrow + ((3 * 4 + quad) ^ l15) * 8);      \
        /* 2. issue t+2 staging (6 gloads; consumed 2 steps later) */          \
        int tn2 = (T) + 2; if (tn2 > kL - 1) tn2 = kL - 1;                     \
        uint8_t* zwb = (ZWR) + w * kZRowB;                                     \
        GL16(zs16, zwb, 0);                                                    \
        GL16(zs16, zwb, 1024);                                                 \
        GL4(zs4, zwb + 2048, 0);                                               \
        GL4(zs4, zwb + 2048, 256);                                             \
        int idn = ids[irow + tn2];                                             \
        const char* rsn = (const char*)embed + (size_t)idn * 1024 + 512        \
                          + lane * 4;                                          \
        uint8_t* rwb = (RWR) + w * kRRowB;                                     \
        GL4(rsn, rwb, 0);                                                      \
        GL4(rsn, rwb, 256);                                                    \
        size_t adv = ((T) + 3 <= kL - 1) ? (size_t)kZStep : 0;                 \
        zs16 += adv; zs4 += adv;                                               \
        /* 3. MFMA: acc += W_h * h */                                          \
        _Pragma("unroll")                                                      \
        for (int g = 0; g < 5; ++g)                                            \
            acc[g] = __builtin_amdgcn_mfma_f32_16x16x32_bf16(wf[g][0], xf0, acc[g], 0, 0, 0); \
        _Pragma("unroll")                                                      \
        for (int g = 0; g < 5; ++g)                                            \
            acc[g] = __builtin_amdgcn_mfma_f32_16x16x32_bf16(wf[g][1], xf1, acc[g], 0, 0, 0); \
        _Pragma("unroll")                                                      \
        for (int g = 0; g < 5; ++g)                                            \
            acc[g] = __builtin_amdgcn_mfma_f32_16x16x32_bf16(wf[g][2], xf2, acc[g], 0, 0, 0); \
        _Pragma("unroll")                                                      \
        for (int g = 0; g < 5; ++g)                                            \
            acc[g] = __builtin_amdgcn_mfma_f32_16x16x32_bf16(wf[g][3], xf3, acc[g], 0, 0, 0); \
        /* 4. gates + h publish */                                             \
        uint16_t hv0, hv1;                                                     \
        GATE_CELL(0, rcv.x, hv0)                                               \
        GATE_CELL(1, rcv.y, hv1)                                               \
        uint32_t hp = (uint32_t)hv0 | ((uint32_t)hv1 << 16);                   \
        *(uint32_t*)&hb[NXT][bl][wlo]     = hp;                                \
        *(uint32_t*)&hb[NXT][bl + 8][whi] = hp;                                \
        /* 5. counted drain: my t+1 loads done; t+2's 6 stay in flight */      \
        asm volatile("s_waitcnt vmcnt(6) lgkmcnt(0)" ::: "memory");            \
        __builtin_amdgcn_sched_barrier(0);                                     \
        __builtin_amdgcn_s_barrier();                                          \
        __builtin_amdgcn_sched_barrier(0);                                     \
    }

#pragma unroll 1
    for (int t2 = 0; t2 < kL; t2 += 2) {
        LSTM_STEP(t2,     0, 1, zA, rA, zC, rC)
        LSTM_STEP(t2 + 1, 1, 0, zB, rB, zA, rA)
        // slots advance by 2: (A,B,C) <- (C,A,B)
        uint8_t* tz = zA; zA = zC; zC = zB; zB = tz;
        uint8_t* tr = rA; rA = rC; rC = rB; rB = tr;
    }
#undef LSTM_STEP
#undef GATE_CELL

    // final: out[b][o] = sum_j h[b][j]*final_w[o][j] + final_b[o]
    // final h is in hb[0] (t=127 wrote NXT=0), swizzled; rows 0..7 valid
    if (tid < kRows * 12) {
        int b = tid / 12, rem = tid % 12;
        int o = rem >> 2, q4 = rem & 3;
        float s = 0.f;
        const float* wrow = final_w + o * kState;
#pragma unroll 8
        for (int j = q4 * 32; j < q4 * 32 + 32; ++j) {
            uint16_t hval = hb[0][b][((j >> 3) ^ b) * 8 + (j & 7)];
            s += bf2f(hval) * wrow[j];
        }
        partial[b][o][q4] = s;
    }
    __syncthreads();
    if (tid < kRows * 3) {
        int b = tid / 3, o = tid % 3;
        float s = partial[b][o][0] + partial[b][o][1] +
                  partial[b][o][2] + partial[b][o][3] + final_b[o];
        out[(b0 + b) * 3 + o] = s;
    }
}

extern "C" void kernel_launch(void* const* d_in, const int* in_sizes, int n_in,
                              void* d_out, int out_size, void* d_ws, size_t ws_size,
                              hipStream_t stream) {
    const int*   ids        = (const int*)d_in[0];
    const float* embed      = (const float*)d_in[1];
    const float* whx_w      = (const float*)d_in[2];
    const float* whx_b      = (const float*)d_in[3];
    const float* init_state = (const float*)d_in[4];
    const float* final_w    = (const float*)d_in[5];
    const float* final_b    = (const float*)d_in[6];
    float*       out        = (float*)d_out;
    uint16_t*    wbf        = (uint16_t*)d_ws;                         // 320 KiB
    float*       zx         = (float*)((char*)d_ws + (size_t)kWElems * 2); // 83.9 MB

    convert_weights_kernel<<<kWElems / 4 / 256, 256, 0, stream>>>(whx_w, wbf);
    zx_gemm_kernel<<<kNTot / 128, 256, 0, stream>>>(wbf, embed, ids, whx_b, zx);
    tree_lstm_kernel<<<kBlocks, kThreads, 0, stream>>>(
        wbf, zx, embed, ids, init_state, final_w, final_b, out);
}

// Round 13
// 236.869 us; speedup vs baseline: 1.3205x; 1.0242x over previous
//
#include <hip/hip_runtime.h>
#include <stdint.h>

// Tree-LSTM scan: B=256, L=128, STATE=128, INIT=256, Z=5*128=640. fp32 I/O.
// Pipeline (2 dispatches; convert kernel deleted in R13):
//  (1) zx_gemm: Zx[t*256+b][640] = W_x @ embed[ids[b,t]][0:128] + bias, fp32.
//      R13: canonical LDS-staged GEMM. 256 blocks = 128 n-blocks x 2
//      j-halves; each block stages its 320x128 bf16 x-part weight slice
//      into LDS ONCE (converted from fp32 whx_w on the fly, XOR-swizzled
//      chunk^=jl&7 so frag reads are 2-way/free), then 8 waves x 2 tiles
//      read frags via ds_read_b128. 2048 waves = 2 waves/SIMD (R12's 1024
//      was 1/SIMD, latency-exposed); weight global traffic 163MB -> 20MB.
//      Per-output math bit-identical to R12 (same f2bf, same MFMA order).
//  (2) scan: 32 blocks x 512 threads, 8 batch rows/block, mirrored MFMA
//      B-cols, W_h register-resident (converted from fp32 in prologue),
//      h LDS XOR-swizzled, raw v_exp_f32 gates, LDS-staged Zx/rc via
//      global_load_lds 2 steps ahead (triple buffer), counted vmcnt(6),
//      one raw barrier per step. 115.8us proven.

constexpr int kL      = 128;
constexpr int kState  = 128;
constexpr int kInit   = 256;
constexpr int kRows   = 8;                      // batch rows per scan block
constexpr int kBlocks = 32;
constexpr int kThreads= 512;
constexpr int kNTot   = 256 * kL;               // 32768 (t,b) rows
constexpr int kZxCols = 5 * kState;             // 640
constexpr int kZRowB  = 2592;                   // LDS zx row stride (bytes)
constexpr int kRRowB  = 520;                    // LDS rc row stride (bytes)
constexpr int kZStep  = 256 * kZxCols * 4;      // 655360 B per t in global zx

typedef __attribute__((ext_vector_type(8))) short short8;    // MFMA A/B frag
typedef __attribute__((ext_vector_type(4))) short short4v;
typedef __attribute__((ext_vector_type(4))) float floatx4;   // MFMA C/D frag

__device__ __forceinline__ uint16_t f2bf(float f) {
    union { float f; uint32_t i; } v; v.f = f;
    return (uint16_t)((v.i + 0x7FFFu + ((v.i >> 16) & 1u)) >> 16);  // RNE
}
__device__ __forceinline__ float bf2f(uint16_t u) {
    union { uint32_t i; float f; } v; v.i = ((uint32_t)u) << 16; return v.f;
}
__device__ __forceinline__ float fexp2(float x) {
    return __builtin_amdgcn_exp2f(x);           // raw v_exp_f32
}

// async global->LDS: dest = wave-uniform base + IMM + lane*size;
// src = per-lane addr + IMM. (IMM applies to BOTH addresses.)
#define GL16(SRC, LDSP, IMM) __builtin_amdgcn_global_load_lds(               \
    (const __attribute__((address_space(1))) uint32_t*)(uintptr_t)(SRC),     \
    (__attribute__((address_space(3))) uint32_t*)(uintptr_t)(LDSP), 16, (IMM), 0)
#define GL4(SRC, LDSP, IMM) __builtin_amdgcn_global_load_lds(                \
    (const __attribute__((address_space(1))) uint32_t*)(uintptr_t)(SRC),     \
    (__attribute__((address_space(3))) uint32_t*)(uintptr_t)(LDSP), 4, (IMM), 0)

// ---- kernel 1: Zx[n][j] = sum_k W[j][128+k]*embed[id(n)][k] + bias[j] ----
// Block b: jhalf = b&1 covers j in [jhalf*320, +320); nblk = b>>1 covers
// n in [nblk*256, +256) (T = nblk). Wave wv: 2 tiles at rows wv*32+{0,16}.
// LDS wl: [320 rows][128 k] bf16, 16B chunk c at (c ^ (jl&7)) within row.
__global__ __launch_bounds__(512)
void zx_gemm_kernel(const float* __restrict__ whx_w,
                    const float* __restrict__ embed,
                    const int* __restrict__ ids,
                    const float* __restrict__ whx_b,
                    float* __restrict__ zx)
{
    __shared__ alignas(16) uint16_t wl[320 * 128];   // 81920 B

    const int tid   = threadIdx.x;
    const int wv    = tid >> 6;
    const int lane  = tid & 63;
    const int l15   = lane & 15;
    const int quad  = lane >> 4;
    const int jhalf = blockIdx.x & 1;
    const int nblk  = blockIdx.x >> 1;

    // gather embed rows for the wave's 2 tiles (overlaps the staging)
    const int n0  = nblk * 256 + wv * 32;
    const int T   = nblk;
    const int B0  = wv * 32 + l15;
    const int id0 = ids[B0 * kL + T];
    const int id1 = ids[(B0 + 16) * kL + T];
    short8 xf0[4], xf1[4];
    {
        const float* xr0 = embed + (size_t)id0 * kInit;   // cols 0..127
        const float* xr1 = embed + (size_t)id1 * kInit;
#pragma unroll
        for (int kk = 0; kk < 4; ++kk) {
            float4 a0 = *(const float4*)(xr0 + kk * 32 + quad * 8);
            float4 a1 = *(const float4*)(xr0 + kk * 32 + quad * 8 + 4);
            uint16_t qa[8] = { f2bf(a0.x), f2bf(a0.y), f2bf(a0.z), f2bf(a0.w),
                               f2bf(a1.x), f2bf(a1.y), f2bf(a1.z), f2bf(a1.w) };
            xf0[kk] = *(short8*)qa;
            float4 b0 = *(const float4*)(xr1 + kk * 32 + quad * 8);
            float4 b1 = *(const float4*)(xr1 + kk * 32 + quad * 8 + 4);
            uint16_t qb[8] = { f2bf(b0.x), f2bf(b0.y), f2bf(b0.z), f2bf(b0.w),
                               f2bf(b1.x), f2bf(b1.y), f2bf(b1.z), f2bf(b1.w) };
            xf1[kk] = *(short8*)qb;
        }
    }

    // stage x-part weights fp32 -> bf16 into LDS (10x 16B chunks/thread)
#pragma unroll
    for (int t = 0; t < 10; ++t) {
        int c   = t * 512 + tid;          // 16B chunk id, 0..5119
        int jl  = c >> 4;                 // local j row 0..319
        int c16 = c & 15;                 // chunk within row
        const float* src = whx_w
            + (size_t)(jhalf * 320 + jl) * kInit + kState + c16 * 8;
        float4 v0 = *(const float4*)(src);
        float4 v1 = *(const float4*)(src + 4);
        uint16_t q[8] = { f2bf(v0.x), f2bf(v0.y), f2bf(v0.z), f2bf(v0.w),
                          f2bf(v1.x), f2bf(v1.y), f2bf(v1.z), f2bf(v1.w) };
        *(short8*)&wl[jl * 128 + ((c16 ^ (jl & 7)) * 8)] = *(short8*)q;
    }
    __syncthreads();

    float* zr0 = zx + (size_t)(n0 + l15) * kZxCols + jhalf * 320;
    float* zr1 = zx + (size_t)(n0 + 16 + l15) * kZxCols + jhalf * 320;
#pragma unroll 5
    for (int jfl = 0; jfl < 20; ++jfl) {
        const uint16_t* base = wl + (size_t)(jfl * 16 + l15) * 128;
        floatx4 bias = *(const floatx4*)(whx_b + jhalf * 320 + jfl * 16 + quad * 4);
        floatx4 acc0 = bias, acc1 = bias;
#pragma unroll
        for (int kk = 0; kk < 4; ++kk) {
            int ch = (kk * 4 + quad) ^ (l15 & 7);
            short8 wa = *(const short8*)(base + ch * 8);
            acc0 = __builtin_amdgcn_mfma_f32_16x16x32_bf16(wa, xf0[kk], acc0, 0, 0, 0);
            acc1 = __builtin_amdgcn_mfma_f32_16x16x32_bf16(wa, xf1[kk], acc1, 0, 0, 0);
        }
        __builtin_nontemporal_store(acc0, (floatx4*)(zr0 + jfl * 16 + quad * 4));
        __builtin_nontemporal_store(acc1, (floatx4*)(zr1 + jfl * 16 + quad * 4));
    }
}

// ---- kernel 2: the scan (h-recurrence only, K=128) ----
__global__ __launch_bounds__(kThreads)
__attribute__((amdgpu_waves_per_eu(1, 2)))
void tree_lstm_kernel(const float* __restrict__ whx_w,
                      const float* __restrict__ zx,
                      const float* __restrict__ embed,
                      const int* __restrict__ ids,
                      const float* __restrict__ init_state,
                      const float* __restrict__ final_w,
                      const float* __restrict__ final_b,
                      float* __restrict__ out)
{
    // h swizzle: (row,col) at [row][ ((col>>3)^row)*8 + (col&7) ]; rows 8..15
    // mirror rows 0..7. Zx/rc tiles: triple-buffered, staged 2 steps ahead.
    __shared__ alignas(16) uint8_t  zxt[3][kRows][kZRowB];  // 62208 B
    __shared__ alignas(8)  uint8_t  rct[3][kRows][kRRowB];  // 12480 B
    __shared__ alignas(16) uint16_t hb[2][16][kState];      //  8192 B
    __shared__ float partial[kRows][3][4];                  //   384 B
    // total 83264 B > 80 KiB => exactly 1 workgroup/CU.

    const int tid  = threadIdx.x;
    const int w    = tid >> 6;        // wave 0..7 -> j-slice [16w,16w+16)
    const int lane = tid & 63;
    const int l15  = lane & 15;       // MFMA D col (batch, mirrored over 8)
    const int quad = lane >> 4;       // 0..3
    const int b0   = blockIdx.x * kRows;
    const int j0   = w * 16 + quad * 4;   // 4 consecutive j (MFMA D rows)
    const int bl   = l15 & 7;             // owned batch row
    const bool hig = l15 >= 8;            // owns r-slots {2,3}
    const int jp   = j0 + (hig ? 2 : 0);  // first owned j
    const int wu   = __builtin_amdgcn_readfirstlane(w);
    const int irow = (b0 + wu) * kL;      // this wave's ids row base

    // lane-const LDS read offsets
    const int zx_rd = bl * kZRowB + j0 * 4;
    const int rc_rd = bl * kRRowB + jp * 4;

    // rotating tile pointers: (A,B,C) = slots (t%3,(t+1)%3,(t+2)%3)
    uint8_t* zA = &zxt[0][0][0]; uint8_t* zB = &zxt[1][0][0]; uint8_t* zC = &zxt[2][0][0];
    uint8_t* rA = &rct[0][0][0]; uint8_t* rB = &rct[1][0][0]; uint8_t* rC = &rct[2][0][0];

    // per-lane global srcs for zx staging (start at t=0, wave's own row)
    const char* zs16 = (const char*)zx + (size_t)(b0 + wu) * (kZxCols * 4) + lane * 16;
    const char* zs4  = (const char*)zx + (size_t)(b0 + wu) * (kZxCols * 4) + 2048 + lane * 4;

    // register-resident A-frags, h-part (cols 0..127), converted from fp32:
    // identical values to the old wbf path (same f2bf).
    short8 wf[5][4];
#pragma unroll
    for (int g = 0; g < 5; ++g) {
        const float* wrow = whx_w + (size_t)(g * 128 + w * 16 + l15) * kInit;
#pragma unroll
        for (int kk = 0; kk < 4; ++kk) {
            float4 a = *(const float4*)(wrow + kk * 32 + quad * 8);
            float4 b = *(const float4*)(wrow + kk * 32 + quad * 8 + 4);
            uint16_t q[8] = { f2bf(a.x), f2bf(a.y), f2bf(a.z), f2bf(a.w),
                              f2bf(b.x), f2bf(b.y), f2bf(b.z), f2bf(b.w) };
            wf[g][kk] = *(short8*)q;
        }
    }

    // h0 (bf16, swizzled into hb[0]) and c0 (fp32 regs for the 2 owned slots)
    const int g8   = 2 * w + (quad >> 1);                // col group of j0/jp
    const int hoff = (g8 ^ l15) * 8 + (quad & 1) * 4;    // h0 write offset
    float c_reg[2];
    {
        uint16_t h0[4];
#pragma unroll
        for (int r = 0; r < 4; ++r)
            h0[r] = f2bf(init_state[j0 + r]);
        c_reg[0] = init_state[128 + jp];
        c_reg[1] = init_state[128 + jp + 1];
        *(short4v*)&hb[0][l15][hoff] = *(short4v*)h0;
    }

    // prologue staging: t=0 -> (zA,rA), t=1 -> (zB,rB).
    // IMM advances BOTH global src and LDS dest together.
    {
        uint8_t* zb0 = zA + w * kZRowB;
        GL16(zs16, zb0, 0);  GL16(zs16, zb0, 1024);
        GL4(zs4, zb0 + 2048, 0); GL4(zs4, zb0 + 2048, 256);
        int id0 = ids[irow + 0];
        const char* rs0 = (const char*)embed + (size_t)id0 * 1024 + 512 + lane * 4;
        uint8_t* rb0 = rA + w * kRRowB;
        GL4(rs0, rb0, 0); GL4(rs0, rb0, 256);
        zs16 += kZStep; zs4 += kZStep;
        uint8_t* zb1 = zB + w * kZRowB;
        GL16(zs16, zb1, 0);  GL16(zs16, zb1, 1024);
        GL4(zs4, zb1 + 2048, 0); GL4(zs4, zb1 + 2048, 256);
        int id1 = ids[irow + 1];
        const char* rs1 = (const char*)embed + (size_t)id1 * 1024 + 512 + lane * 4;
        uint8_t* rb1 = rB + w * kRRowB;
        GL4(rs1, rb1, 0); GL4(rs1, rb1, 256);
        zs16 += kZStep; zs4 += kZStep;           // now points at t=2
    }
    __syncthreads();   // full drain: h0 + tiles t=0,1 resident

    // per-step h write: 2 bf16 (4 B) to row bl AND mirror row bl+8
    const int eoff  = (quad & 1) * 4 + (hig ? 2 : 0);    // jp & 7
    const int wlo   = (g8 ^ bl) * 8 + eoff;
    const int whi   = ((g8 ^ bl) ^ 8) * 8 + eoff;

    const float K1 = 1.442695041f;   // log2(e)
    const float K2 = 2.885390082f;   // 2*log2(e)

    // fminf-only clamps: unclamped directions safe (Inf -> rcp -> 0).
#define GATE_CELL(RL, RCV, HVOUT)                                              \
    {                                                                          \
        float ga = hig ? acc[0][RL + 2] : acc[0][RL];                          \
        float gi = hig ? acc[1][RL + 2] : acc[1][RL];                          \
        float g1 = hig ? acc[2][RL + 2] : acc[2][RL];                          \
        float g2 = hig ? acc[3][RL + 2] : acc[3][RL];                          \
        float go = hig ? acc[4][RL + 2] : acc[4][RL];                          \
        float a  = fminf(ga, 15.f);                                            \
        float f1 = fminf(g1, 30.f);                                            \
        float f2 = fminf(g2, 30.f);                                            \
        float Ea = fexp2(a * K2);                 /* e^{2a} */                 \
        float Ei = fexp2(-gi * K1);               /* e^{-i} */                 \
        float P  = (Ea - 1.0f) *                                               \
            __builtin_amdgcn_rcpf((Ea + 1.0f) * (1.0f + Ei));                  \
        float E1 = fexp2(f1 * K1), E2 = fexp2(f2 * K1);                        \
        float lc = c_reg[RL], rc = (RCV);                                      \
        float num = E1 * (1.0f + E2) * lc + E2 * (1.0f + E1) * rc;             \
        float Q  = num * __builtin_amdgcn_rcpf((1.0f + E1) * (1.0f + E2));     \
        float c  = P + Q;                                                      \
        c_reg[RL] = c;                                                         \
        float Eo = fexp2(-go * K1);                                            \
        float cc = fminf(c, 15.f);                                             \
        float Ec = fexp2(cc * K2);                                             \
        float h  = (Ec - 1.0f) *                                               \
            __builtin_amdgcn_rcpf((1.0f + Eo) * (Ec + 1.0f));                  \
        HVOUT = f2bf(h);                                                       \
    }

#define LSTM_STEP(T, CUR, NXT, ZRD, RRD, ZWR, RWR)                             \
    {                                                                          \
        /* 1. tile ds_reads FIRST (outstanding vmem = t+1's, already landed)*/ \
        const uint8_t* zrow = (ZRD) + zx_rd;                                   \
        floatx4 acc[5];                                                        \
        _Pragma("unroll")                                                      \
        for (int g = 0; g < 5; ++g)                                            \
            acc[g] = *(const floatx4*)(zrow + g * 512);                        \
        float2 rcv = *(const float2*)((RRD) + rc_rd);                          \
        const uint16_t* hrow = &hb[CUR][l15][0];                               \
        short8 xf0 = *(const short8*)(hrow + ((0 * 4 + quad) ^ l15) * 8);      \
        short8 xf1 = *(const short8*)(hrow + ((1 * 4 + quad) ^ l15) * 8);      \
        short8 xf2 = *(const short8*)(hrow + ((2 * 4 + quad) ^ l15) * 8);      \
        short8 xf3 = *(const short8*)(hrow + ((3 * 4 + quad) ^ l15) * 8);      \
        /* 2. issue t+2 staging (6 gloads; consumed 2 steps later) */          \
        int tn2 = (T) + 2; if (tn2 > kL - 1) tn2 = kL - 1;                     \
        uint8_t* zwb = (ZWR) + w * kZRowB;                                     \
        GL16(zs16, zwb, 0);                                                    \
        GL16(zs16, zwb, 1024);                                                 \
        GL4(zs4, zwb + 2048, 0);                                               \
        GL4(zs4, zwb + 2048, 256);                                             \
        int idn = ids[irow + tn2];                                             \
        const char* rsn = (const char*)embed + (size_t)idn * 1024 + 512        \
                          + lane * 4;                                          \
        uint8_t* rwb = (RWR) + w * kRRowB;                                     \
        GL4(rsn, rwb, 0);                                                      \
        GL4(rsn, rwb, 256);                                                    \
        size_t adv = ((T) + 3 <= kL - 1) ? (size_t)kZStep : 0;                 \
        zs16 += adv; zs4 += adv;                                               \
        /* 3. MFMA: acc += W_h * h */                                          \
        _Pragma("unroll")                                                      \
        for (int g = 0; g < 5; ++g)                                            \
            acc[g] = __builtin_amdgcn_mfma_f32_16x16x32_bf16(wf[g][0], xf0, acc[g], 0, 0, 0); \
        _Pragma("unroll")                                                      \
        for (int g = 0; g < 5; ++g)                                            \
            acc[g] = __builtin_amdgcn_mfma_f32_16x16x32_bf16(wf[g][1], xf1, acc[g], 0, 0, 0); \
        _Pragma("unroll")                                                      \
        for (int g = 0; g < 5; ++g)                                            \
            acc[g] = __builtin_amdgcn_mfma_f32_16x16x32_bf16(wf[g][2], xf2, acc[g], 0, 0, 0); \
        _Pragma("unroll")                                                      \
        for (int g = 0; g < 5; ++g)                                            \
            acc[g] = __builtin_amdgcn_mfma_f32_16x16x32_bf16(wf[g][3], xf3, acc[g], 0, 0, 0); \
        /* 4. gates + h publish */                                             \
        uint16_t hv0, hv1;                                                     \
        GATE_CELL(0, rcv.x, hv0)                                               \
        GATE_CELL(1, rcv.y, hv1)                                               \
        uint32_t hp = (uint32_t)hv0 | ((uint32_t)hv1 << 16);                   \
        *(uint32_t*)&hb[NXT][bl][wlo]     = hp;                                \
        *(uint32_t*)&hb[NXT][bl + 8][whi] = hp;                                \
        /* 5. counted drain: my t+1 loads done; t+2's 6 stay in flight */      \
        asm volatile("s_waitcnt vmcnt(6) lgkmcnt(0)" ::: "memory");            \
        __builtin_amdgcn_sched_barrier(0);                                     \
        __builtin_amdgcn_s_barrier();                                          \
        __builtin_amdgcn_sched_barrier(0);                                     \
    }

#pragma unroll 1
    for (int t2 = 0; t2 < kL; t2 += 2) {
        LSTM_STEP(t2,     0, 1, zA, rA, zC, rC)
        LSTM_STEP(t2 + 1, 1, 0, zB, rB, zA, rA)
        // slots advance by 2: (A,B,C) <- (C,A,B)
        uint8_t* tz = zA; zA = zC; zC = zB; zB = tz;
        uint8_t* tr = rA; rA = rC; rC = rB; rB = tr;
    }
#undef LSTM_STEP
#undef GATE_CELL

    // final: out[b][o] = sum_j h[b][j]*final_w[o][j] + final_b[o]
    // final h is in hb[0] (t=127 wrote NXT=0), swizzled; rows 0..7 valid
    if (tid < kRows * 12) {
        int b = tid / 12, rem = tid % 12;
        int o = rem >> 2, q4 = rem & 3;
        float s = 0.f;
        const float* wrow = final_w + o * kState;
#pragma unroll 8
        for (int j = q4 * 32; j < q4 * 32 + 32; ++j) {
            uint16_t hval = hb[0][b][((j >> 3) ^ b) * 8 + (j & 7)];
            s += bf2f(hval) * wrow[j];
        }
        partial[b][o][q4] = s;
    }
    __syncthreads();
    if (tid < kRows * 3) {
        int b = tid / 3, o = tid % 3;
        float s = partial[b][o][0] + partial[b][o][1] +
                  partial[b][o][2] + partial[b][o][3] + final_b[o];
        out[(b0 + b) * 3 + o] = s;
    }
}

extern "C" void kernel_launch(void* const* d_in, const int* in_sizes, int n_in,
                              void* d_out, int out_size, void* d_ws, size_t ws_size,
                              hipStream_t stream) {
    const int*   ids        = (const int*)d_in[0];
    const float* embed      = (const float*)d_in[1];
    const float* whx_w      = (const float*)d_in[2];
    const float* whx_b      = (const float*)d_in[3];
    const float* init_state = (const float*)d_in[4];
    const float* final_w    = (const float*)d_in[5];
    const float* final_b    = (const float*)d_in[6];
    float*       out        = (float*)d_out;
    float*       zx         = (float*)d_ws;                            // 83.9 MB

    zx_gemm_kernel<<<256, 512, 0, stream>>>(whx_w, embed, ids, whx_b, zx);
    tree_lstm_kernel<<<kBlocks, kThreads, 0, stream>>>(
        whx_w, zx, embed, ids, init_state, final_w, final_b, out);
}